// Round 1
// 1545.706 us; speedup vs baseline: 1.3862x; 1.3862x over previous
//
#include <hip/hip_runtime.h>
#include <hip/hip_fp16.h>

// Sinkhorn OT: B=128, N=M=1024, eps=0.05, stab=1e-8, 10 iters.
// K cached as fp16 in ws (256MB). One fused kernel per iteration: each block
// owns 16 rows of one batch, stages fp16 K-tile in LDS, computes u for its
// rows (wave dot vs register-resident v), then writes its K^T u partial
// NON-atomically to a (B,64,M) partials buffer; k_vred folds 64->1 -> v.
// First iteration fuses k_setup: reads C, writes Kh, uses v0=1/M constant.
// Fallbacks: atomic path (ws too small for partials), from-C path (no Kh).

#define BB 128
#define NN 1024
#define MM 1024
#define RR 16          // rows per block in iteration kernel
#define ITERS 10

// ---------------- fast path (no atomics) ----------------

// MODE 0: first iter — read C, write Kh, v = 1/M constant, partial out.
// MODE 1: steady     — read Kh, v from global, partial out.
template<int MODE>
__global__ __launch_bounds__(256) void k_iterP(const float* __restrict__ C,
                                               __half* __restrict__ Kh,
                                               const float* __restrict__ v,
                                               float* __restrict__ u,
                                               float* __restrict__ P) {
    __shared__ __align__(16) __half tile[RR][MM];   // 32 KB
    __shared__ __align__(16) float  v_s[MM];        // 4 KB
    __shared__ float u_s[RR];

    int b    = blockIdx.x >> 6;    // / (NN/RR)
    int rb   = blockIdx.x & 63;
    int row0 = rb * RR;
    int tid  = threadIdx.x;
    int wave = tid >> 6, lane = tid & 63;

    float vr[16];
    if (MODE == 1) {
        const float* vb = v + ((size_t)b << 10);
        *(float4*)&v_s[tid * 4] = *(const float4*)&vb[tid * 4];
        __syncthreads();
#pragma unroll
        for (int j = 0; j < 2; ++j) {
            *(float4*)&vr[8 * j]     = *(float4*)&v_s[j * 512 + lane * 8];
            *(float4*)&vr[8 * j + 4] = *(float4*)&v_s[j * 512 + lane * 8 + 4];
        }
    }

    // Phase A: u[n] = 1/(K[n,:]·v + stab); stage K rows in LDS as fp16.
    for (int r = wave; r < RR; r += 4) {
        int n = row0 + r;
        size_t rowoff = ((size_t)b * NN + n) * MM;
        float sum = 0.0f;
        if (MODE == 1) {
            const __half* kr = Kh + rowoff;
            uint4 p0 = *(const uint4*)(kr + lane * 8);         // 8 halves
            uint4 p1 = *(const uint4*)(kr + 512 + lane * 8);   // 8 halves
            *(uint4*)&tile[r][lane * 8]       = p0;
            *(uint4*)&tile[r][512 + lane * 8] = p1;
            const __half2* h0 = (const __half2*)&p0;
            const __half2* h1 = (const __half2*)&p1;
#pragma unroll
            for (int j = 0; j < 4; ++j) {
                float2 f0 = __half22float2(h0[j]);
                float2 f1 = __half22float2(h1[j]);
                sum += f0.x * vr[2 * j] + f0.y * vr[2 * j + 1];
                sum += f1.x * vr[8 + 2 * j] + f1.y * vr[8 + 2 * j + 1];
            }
        } else {
            const float* cr = C + rowoff;
            float cv[16];
            *(float4*)&cv[0]  = *(const float4*)(cr + lane * 8);
            *(float4*)&cv[4]  = *(const float4*)(cr + lane * 8 + 4);
            *(float4*)&cv[8]  = *(const float4*)(cr + 512 + lane * 8);
            *(float4*)&cv[12] = *(const float4*)(cr + 512 + lane * 8 + 4);
            __half hh[16];
#pragma unroll
            for (int j = 0; j < 16; ++j) {
                float kk = __expf(cv[j] * -20.0f);
                sum += kk;                       // v0 = 1/M applied below
                hh[j] = __float2half(kk);
            }
            sum *= (1.0f / 1024.0f);
            *(uint4*)&tile[r][lane * 8]       = *(uint4*)&hh[0];
            *(uint4*)&tile[r][512 + lane * 8] = *(uint4*)&hh[8];
            *(uint4*)(Kh + rowoff + lane * 8)       = *(uint4*)&hh[0];
            *(uint4*)(Kh + rowoff + 512 + lane * 8) = *(uint4*)&hh[8];
        }
#pragma unroll
        for (int off = 32; off > 0; off >>= 1) sum += __shfl_down(sum, off);
        if (lane == 0) {
            float uu = 1.0f / (sum + 1e-8f);
            u_s[r] = uu;
            u[(size_t)b * NN + n] = uu;
        }
    }
    __syncthreads();

    // Phase B: P[b,rb,m] = sum_{n in tile} K[n,m]*u[n]; thread owns 4 cols.
    float a0 = 0.f, a1 = 0.f, a2 = 0.f, a3 = 0.f;
    int c0 = tid * 4;
#pragma unroll
    for (int r = 0; r < RR; ++r) {
        float uu = u_s[r];
        uint2 p = *(const uint2*)&tile[r][c0];
        float2 f0 = __half22float2(*(__half2*)&p.x);
        float2 f1 = __half22float2(*(__half2*)&p.y);
        a0 += f0.x * uu; a1 += f0.y * uu;
        a2 += f1.x * uu; a3 += f1.y * uu;
    }
    *(float4*)(P + (((size_t)b * 64 + rb) << 10) + c0) =
        make_float4(a0, a1, a2, a3);
}

// v[b,m] = 1/(sum_j P[b,j,m] + eps); 65536 threads, 2 cols each.
__global__ __launch_bounds__(256) void k_vred(const float* __restrict__ P,
                                              float* __restrict__ v) {
    int t = blockIdx.x * 256 + threadIdx.x;
    int b = t >> 9;
    int m = (t & 511) * 2;
    const float* p = P + ((size_t)b << 16) + m;
    float2 s = *(const float2*)p;
#pragma unroll 8
    for (int j = 1; j < 64; ++j) {
        float2 q = *(const float2*)(p + ((size_t)j << 10));
        s.x += q.x; s.y += q.y;
    }
    float2 o = make_float2(1.0f / (s.x + 1e-8f), 1.0f / (s.y + 1e-8f));
    *(float2*)(v + ((size_t)b << 10) + m) = o;
}

// ---------------- fallback path (atomic, as before) ----------------

__global__ __launch_bounds__(256) void k_init(float* __restrict__ v,
                                              float* __restrict__ vacc) {
    int i = blockIdx.x * 256 + threadIdx.x;
    v[i] = 1.0f / 1024.0f;
    vacc[i] = 0.0f;
}

__global__ __launch_bounds__(256) void k_setup(const float* __restrict__ C,
                                               __half* __restrict__ Kh) {
    size_t i = ((size_t)blockIdx.x * 256 + threadIdx.x) * 8;
    float4 a = *(const float4*)(C + i);
    float4 b = *(const float4*)(C + i + 4);
    __half2 h[4];
    h[0] = __floats2half2_rn(__expf(a.x * -20.0f), __expf(a.y * -20.0f));
    h[1] = __floats2half2_rn(__expf(a.z * -20.0f), __expf(a.w * -20.0f));
    h[2] = __floats2half2_rn(__expf(b.x * -20.0f), __expf(b.y * -20.0f));
    h[3] = __floats2half2_rn(__expf(b.z * -20.0f), __expf(b.w * -20.0f));
    *(uint4*)(Kh + i) = *(uint4*)h;
}

template<bool FROM_C>
__global__ __launch_bounds__(256) void k_iter(const void* __restrict__ Ksrc,
                                              const float* __restrict__ v,
                                              float* __restrict__ u,
                                              float* __restrict__ vacc) {
    __shared__ __align__(16) __half tile[RR][MM];
    __shared__ __align__(16) float  v_s[MM];
    __shared__ float u_s[RR];

    int b    = blockIdx.x >> 6;
    int rb   = blockIdx.x & 63;
    int row0 = rb * RR;
    int tid  = threadIdx.x;
    int wave = tid >> 6, lane = tid & 63;

    {
        const float* vb = v + ((size_t)b << 10);
        *(float4*)&v_s[tid * 4] = *(const float4*)&vb[tid * 4];
    }
    __syncthreads();

    float vr[16];
#pragma unroll
    for (int j = 0; j < 2; ++j) {
        *(float4*)&vr[8 * j]     = *(float4*)&v_s[j * 512 + lane * 8];
        *(float4*)&vr[8 * j + 4] = *(float4*)&v_s[j * 512 + lane * 8 + 4];
    }

    for (int r = wave; r < RR; r += 4) {
        int n = row0 + r;
        size_t rowoff = ((size_t)b * NN + n) * MM;
        float sum = 0.0f;
        if (!FROM_C) {
            const __half* kr = (const __half*)Ksrc + rowoff;
            uint4 p0 = *(const uint4*)(kr + lane * 8);
            uint4 p1 = *(const uint4*)(kr + 512 + lane * 8);
            *(uint4*)&tile[r][lane * 8]       = p0;
            *(uint4*)&tile[r][512 + lane * 8] = p1;
            const __half2* h0 = (const __half2*)&p0;
            const __half2* h1 = (const __half2*)&p1;
#pragma unroll
            for (int j = 0; j < 4; ++j) {
                float2 f0 = __half22float2(h0[j]);
                float2 f1 = __half22float2(h1[j]);
                sum += f0.x * vr[2 * j] + f0.y * vr[2 * j + 1];
                sum += f1.x * vr[8 + 2 * j] + f1.y * vr[8 + 2 * j + 1];
            }
        } else {
            const float* cr = (const float*)Ksrc + rowoff;
            float cv[16];
            *(float4*)&cv[0]  = *(const float4*)(cr + lane * 8);
            *(float4*)&cv[4]  = *(const float4*)(cr + lane * 8 + 4);
            *(float4*)&cv[8]  = *(const float4*)(cr + 512 + lane * 8);
            *(float4*)&cv[12] = *(const float4*)(cr + 512 + lane * 8 + 4);
            __half hh[16];
#pragma unroll
            for (int j = 0; j < 16; ++j) {
                float kk = __expf(cv[j] * -20.0f);
                sum += kk * vr[j];
                hh[j] = __float2half(kk);
            }
            *(uint4*)&tile[r][lane * 8]       = *(uint4*)&hh[0];
            *(uint4*)&tile[r][512 + lane * 8] = *(uint4*)&hh[8];
        }
#pragma unroll
        for (int off = 32; off > 0; off >>= 1) sum += __shfl_down(sum, off);
        if (lane == 0) {
            float uu = 1.0f / (sum + 1e-8f);
            u_s[r] = uu;
            u[(size_t)b * NN + n] = uu;
        }
    }
    __syncthreads();

    float a0 = 0.f, a1 = 0.f, a2 = 0.f, a3 = 0.f;
    int c0 = tid * 4;
#pragma unroll
    for (int r = 0; r < RR; ++r) {
        float uu = u_s[r];
        uint2 p = *(const uint2*)&tile[r][c0];
        float2 f0 = __half22float2(*(__half2*)&p.x);
        float2 f1 = __half22float2(*(__half2*)&p.y);
        a0 += f0.x * uu; a1 += f0.y * uu;
        a2 += f1.x * uu; a3 += f1.y * uu;
    }
    float* dst = vacc + ((size_t)b << 10) + c0;
    atomicAdd(dst + 0, a0);
    atomicAdd(dst + 1, a1);
    atomicAdd(dst + 2, a2);
    atomicAdd(dst + 3, a3);
}

__global__ __launch_bounds__(256) void k_vupd(float* __restrict__ v,
                                              float* __restrict__ vacc) {
    int i = blockIdx.x * 256 + threadIdx.x;
    v[i] = 1.0f / (vacc[i] + 1e-8f);
    vacc[i] = 0.0f;
}

// ---------------- finals ----------------

__global__ __launch_bounds__(256) void k_final_h(const __half* __restrict__ Kh,
                                                 const float* __restrict__ u,
                                                 const float* __restrict__ v,
                                                 float* __restrict__ out) {
    size_t i = ((size_t)blockIdx.x * 256 + threadIdx.x) * 8;
    size_t row = i >> 10;              // b*N + n
    int b = (int)(row >> 10);
    int m = (int)(i & 1023);
    float uu = u[row];
    const float* vb = v + ((size_t)b << 10) + m;
    float4 v0 = *(const float4*)(vb);
    float4 v1 = *(const float4*)(vb + 4);
    uint4 kp = *(const uint4*)(Kh + i);
    __half2* h = (__half2*)&kp;
    float2 f0 = __half22float2(h[0]), f1 = __half22float2(h[1]);
    float2 f2 = __half22float2(h[2]), f3 = __half22float2(h[3]);
    float4 o0, o1;
    o0.x = uu * f0.x * v0.x; o0.y = uu * f0.y * v0.y;
    o0.z = uu * f1.x * v0.z; o0.w = uu * f1.y * v0.w;
    o1.x = uu * f2.x * v1.x; o1.y = uu * f2.y * v1.y;
    o1.z = uu * f3.x * v1.z; o1.w = uu * f3.y * v1.w;
    *(float4*)(out + i)     = o0;
    *(float4*)(out + i + 4) = o1;
}

__global__ __launch_bounds__(256) void k_final_c(const float* __restrict__ C,
                                                 const float* __restrict__ u,
                                                 const float* __restrict__ v,
                                                 float* __restrict__ out) {
    size_t i = ((size_t)blockIdx.x * 256 + threadIdx.x) * 8;
    size_t row = i >> 10;
    int b = (int)(row >> 10);
    int m = (int)(i & 1023);
    float uu = u[row];
    const float* vb = v + ((size_t)b << 10) + m;
    float4 v0 = *(const float4*)(vb);
    float4 v1 = *(const float4*)(vb + 4);
    float4 c0 = *(const float4*)(C + i);
    float4 c1 = *(const float4*)(C + i + 4);
    float4 o0, o1;
    o0.x = uu * __expf(c0.x * -20.0f) * v0.x;
    o0.y = uu * __expf(c0.y * -20.0f) * v0.y;
    o0.z = uu * __expf(c0.z * -20.0f) * v0.z;
    o0.w = uu * __expf(c0.w * -20.0f) * v0.w;
    o1.x = uu * __expf(c1.x * -20.0f) * v1.x;
    o1.y = uu * __expf(c1.y * -20.0f) * v1.y;
    o1.z = uu * __expf(c1.z * -20.0f) * v1.z;
    o1.w = uu * __expf(c1.w * -20.0f) * v1.w;
    *(float4*)(out + i)     = o0;
    *(float4*)(out + i + 4) = o1;
}

extern "C" void kernel_launch(void* const* d_in, const int* in_sizes, int n_in,
                              void* d_out, int out_size, void* d_ws, size_t ws_size,
                              hipStream_t stream) {
    const float* C = (const float*)d_in[0];
    float* out = (float*)d_out;

    const size_t kBytes = (size_t)BB * NN * MM * sizeof(__half);   // 256 MB
    const size_t pBytes = (size_t)BB * 64 * MM * sizeof(float);    // 32 MB
    const size_t vecB   = (size_t)BB * MM * sizeof(float);         // 512 KB

    const bool fast2 = ws_size >= kBytes + pBytes + 2 * vecB;
    const bool fast  = ws_size >= kBytes + 3 * vecB;

    const int nElem    = BB * NN * MM;
    const int gridElem = nElem / (256 * 8);       // 65536
    const int gridVec  = (BB * MM) / 256;         // 512
    const int gridIter = BB * (NN / RR);          // 8192

    char* w = (char*)d_ws;
    if (fast2) {
        __half* Kh = (__half*)w;
        float*  P  = (float*)(w + kBytes);
        float*  u  = (float*)(w + kBytes + pBytes);
        float*  v  = (float*)(w + kBytes + pBytes + vecB);

        k_iterP<0><<<gridIter, 256, 0, stream>>>(C, Kh, nullptr, u, P);
        k_vred<<<256, 256, 0, stream>>>(P, v);
        for (int t = 1; t < ITERS; ++t) {
            k_iterP<1><<<gridIter, 256, 0, stream>>>(nullptr, Kh, v, u, P);
            k_vred<<<256, 256, 0, stream>>>(P, v);
        }
        k_final_h<<<gridElem, 256, 0, stream>>>(Kh, u, v, out);
    } else if (fast) {
        __half* Kh = (__half*)w;
        float*  u    = (float*)(w + kBytes);
        float*  v    = (float*)(w + kBytes + vecB);
        float*  vacc = (float*)(w + kBytes + 2 * vecB);
        k_init<<<gridVec, 256, 0, stream>>>(v, vacc);
        k_setup<<<gridElem, 256, 0, stream>>>(C, Kh);
        for (int t = 0; t < ITERS; ++t) {
            k_iter<false><<<gridIter, 256, 0, stream>>>((const void*)Kh, v, u, vacc);
            k_vupd<<<gridVec, 256, 0, stream>>>(v, vacc);
        }
        k_final_h<<<gridElem, 256, 0, stream>>>(Kh, u, v, out);
    } else {
        float* u    = (float*)w;
        float* v    = (float*)(w + vecB);
        float* vacc = (float*)(w + 2 * vecB);
        k_init<<<gridVec, 256, 0, stream>>>(v, vacc);
        for (int t = 0; t < ITERS; ++t) {
            k_iter<true><<<gridIter, 256, 0, stream>>>((const void*)C, v, u, vacc);
            k_vupd<<<gridVec, 256, 0, stream>>>(v, vacc);
        }
        k_final_c<<<gridElem, 256, 0, stream>>>(C, u, v, out);
    }
}